// Round 3
// baseline (158.419 us; speedup 1.0000x reference)
//
#include <hip/hip_runtime.h>

static constexpr int Vn = 1024;   // codebook size
static constexpr int Dn = 256;    // code dim
static constexpr int NT = 65536;  // B * TOK

typedef float vfloat4 __attribute__((ext_vector_type(4)));  // native vec for stores

// ---------------------------------------------------------------------------
// Kernel 1: G = W * W^T (1024x1024, K=256), fp32. Unchanged from round 2
// (passing): [k][m] LDS (stride 68), ds_read_b128 fragments, reg-prefetched
// staging, nt G stores. fmaf chain k=0..255 ascending -> bit-identical G/norms.
// ---------------------------------------------------------------------------
__global__ __launch_bounds__(256) void gram_kernel(const float* __restrict__ W,
                                                   float* __restrict__ G,
                                                   float* __restrict__ norms) {
    __shared__ float As[32][68];
    __shared__ float Bs[32][68];
    const int tid = threadIdx.x;
    const int tx = tid & 15;
    const int ty = tid >> 4;
    const int bm = blockIdx.y * 64;
    const int bn = blockIdx.x * 64;
    const float4* Wv = (const float4*)W;

    const int m0  = tid >> 3;
    const int kql = tid & 7;

    float4 pa[2], pb[2];
#pragma unroll
    for (int s = 0; s < 2; ++s) {
        pa[s] = Wv[(bm + m0 + 32 * s) * 64 + kql];
        pb[s] = Wv[(bn + m0 + 32 * s) * 64 + kql];
    }

    float acc[4][4] = {};
    for (int c = 0; c < 8; ++c) {
#pragma unroll
        for (int s = 0; s < 2; ++s) {
            const int m = m0 + 32 * s;
            As[kql * 4 + 0][m] = pa[s].x;
            As[kql * 4 + 1][m] = pa[s].y;
            As[kql * 4 + 2][m] = pa[s].z;
            As[kql * 4 + 3][m] = pa[s].w;
            Bs[kql * 4 + 0][m] = pb[s].x;
            Bs[kql * 4 + 1][m] = pb[s].y;
            Bs[kql * 4 + 2][m] = pb[s].z;
            Bs[kql * 4 + 3][m] = pb[s].w;
        }
        __syncthreads();
        if (c < 7) {
            const int kq = (c + 1) * 8 + kql;
#pragma unroll
            for (int s = 0; s < 2; ++s) {
                pa[s] = Wv[(bm + m0 + 32 * s) * 64 + kq];
                pb[s] = Wv[(bn + m0 + 32 * s) * 64 + kq];
            }
        }
        const float* Ab = &As[0][ty * 4];
        const float* Bb = &Bs[0][tx * 4];
        float4 a_c = *(const float4*)Ab;
        float4 b_c = *(const float4*)Bb;
#pragma unroll
        for (int kk = 0; kk < 32; ++kk) {
            const int kn = (kk < 31) ? kk + 1 : kk;
            const float4 a_n = *(const float4*)(Ab + kn * 68);
            const float4 b_n = *(const float4*)(Bb + kn * 68);
            const float a_s[4] = {a_c.x, a_c.y, a_c.z, a_c.w};
            const float b_s[4] = {b_c.x, b_c.y, b_c.z, b_c.w};
#pragma unroll
            for (int u = 0; u < 4; ++u)
#pragma unroll
                for (int w = 0; w < 4; ++w)
                    acc[u][w] = fmaf(a_s[u], b_s[w], acc[u][w]);
            a_c = a_n;
            b_c = b_n;
        }
        __syncthreads();
    }
#pragma unroll
    for (int u = 0; u < 4; ++u) {
        const int row = bm + ty * 4 + u;
        vfloat4 o;
        o.x = acc[u][0]; o.y = acc[u][1]; o.z = acc[u][2]; o.w = acc[u][3];
        __builtin_nontemporal_store(o, (vfloat4*)(G + row * Vn + bn + tx * 4));
        if (bm == bn && tx == ty) norms[row] = acc[u][u];
    }
}

// ---------------------------------------------------------------------------
// Kernel 2 (NEW): i-bucketed argmin. Block c owns code value c: G[c] and norms
// live in REGISTERS (loaded once per block), so each token costs only ONE
// G-row read (G[seq2[t]], 4 KB) instead of two -> G traffic 512 MB -> 260 MB.
// Tokens are found by scanning seq with int4 loads (256 KB, L2-broadcast);
// no histogram/scatter kernels, no atomics, no zero-init (poison-safe).
// EXACTNESS: per-token score chain, lane->v mapping, strict-< first-min update
// order, and the 64-lane lexicographic reduce are copied verbatim from the
// passing kernel -> bit-identical bestV for every token.
// ---------------------------------------------------------------------------
__global__ __launch_bounds__(256) void argmin_bucket_kernel(const int* __restrict__ seq,
                                                            const int* __restrict__ seq2,
                                                            const float* __restrict__ alpha,
                                                            const float* __restrict__ G,
                                                            const float* __restrict__ norms,
                                                            int* __restrict__ bestV) {
    const int c    = blockIdx.x;      // code value this block owns (i-side)
    const int tid  = threadIdx.x;
    const int w    = tid >> 6;        // wave 0..3
    const int lane = tid & 63;

    // per-lane fragments of norms and G[c]: 16 v-slots each, in registers
    float4 nn_r[4], gi_r[4];
    const float4* Gi = (const float4*)(G + c * Vn);
#pragma unroll
    for (int s = 0; s < 4; ++s) {
        nn_r[s] = ((const float4*)norms)[s * 64 + lane];
        gi_r[s] = Gi[s * 64 + lane];
    }

    const float a  = alpha[0];
    const float c0 = -2.0f * (1.0f - a);
    const float c1 = -2.0f * a;

    const int4* seq4 = (const int4*)seq;   // 16384 int4 = 65536 tokens
    for (int it = 0; it < 64; ++it) {
        const int idx4 = tid + 256 * it;   // per wave-iter: 1 KB contiguous
        const int4 v4 = seq4[idx4];
        const int sub = (v4.x == c ? 1 : 0) | (v4.y == c ? 2 : 0) |
                        (v4.z == c ? 4 : 0) | (v4.w == c ? 8 : 0);
        unsigned long long mask = __ballot(sub != 0);
        while (mask) {                     // wave-uniform; rare (avg 64/block)
            const int src = __builtin_ctzll((unsigned long long)mask);
            mask &= mask - 1;
            const int smask = __shfl(sub, src, 64);
            const int tbase = 4 * (w * 64 + src + 256 * it);
#pragma unroll
            for (int q = 0; q < 4; ++q) {
                if (!(smask & (1 << q))) continue;   // wave-uniform
                const int t = tbase + q;
                const int j = seq2[t];               // broadcast load
                const float4* Gj = (const float4*)(G + j * Vn);
                float best = __builtin_inff();
                int vbest = 0;
#pragma unroll
                for (int s = 0; s < 4; ++s) {
                    const float4 gj = Gj[s * 64 + lane];
                    const float4 gi = gi_r[s];
                    const float4 nn = nn_r[s];
                    const int v = (s * 64 + lane) * 4;
                    const float s0 = fmaf(c1, gj.x, fmaf(c0, gi.x, nn.x));
                    const float s1 = fmaf(c1, gj.y, fmaf(c0, gi.y, nn.y));
                    const float s2 = fmaf(c1, gj.z, fmaf(c0, gi.z, nn.z));
                    const float s3 = fmaf(c1, gj.w, fmaf(c0, gi.w, nn.w));
                    if (s0 < best) { best = s0; vbest = v; }
                    if (s1 < best) { best = s1; vbest = v + 1; }
                    if (s2 < best) { best = s2; vbest = v + 2; }
                    if (s3 < best) { best = s3; vbest = v + 3; }
                }
#pragma unroll
                for (int off = 32; off >= 1; off >>= 1) {
                    const float ob = __shfl_down(best, off, 64);
                    const int   vb = __shfl_down(vbest, off, 64);
                    if (ob < best || (ob == best && vb < vbest)) { best = ob; vbest = vb; }
                }
                if (lane == 0) bestV[t] = vbest;
            }
        }
    }
}

// ---------------------------------------------------------------------------
// Kernel 3: output writer = old phase 2 verbatim, bestV from global.
// Block = 32 consecutive tokens; LDS transpose; 128 B nt store lines.
// ---------------------------------------------------------------------------
__global__ __launch_bounds__(256) void write_kernel(const int* __restrict__ bestV,
                                                    const float* __restrict__ W,
                                                    float* __restrict__ out) {
    __shared__ float T[32][129];
    const int tid = threadIdx.x;
    const int t0  = blockIdx.x * 32;
    const int b   = t0 >> 8;
    const int hw0 = t0 & 255;
    float* outb = out + b * 65536 + hw0;
    const int tok  = tid >> 3;
    const int l8   = tid & 7;
    const int hw4  = (tid & 7) * 4;
    const int drow = tid >> 3;
    const int v = bestV[t0 + tok];        // 8 lanes/token broadcast
#pragma unroll
    for (int half = 0; half < 2; ++half) {
        const float4* Wr = (const float4*)(W + v * Dn + half * 128);
#pragma unroll
        for (int p = 0; p < 4; ++p) {
            const int d4 = p * 8 + l8;
            const float4 w4 = Wr[d4];
            T[tok][d4 * 4 + 0] = w4.x;
            T[tok][d4 * 4 + 1] = w4.y;
            T[tok][d4 * 4 + 2] = w4.z;
            T[tok][d4 * 4 + 3] = w4.w;
        }
        __syncthreads();
#pragma unroll
        for (int dp = 0; dp < 128; dp += 32) {
            const int dl = dp + drow;
            const int d = half * 128 + dl;
            vfloat4 o;
            o.x = T[hw4 + 0][dl];
            o.y = T[hw4 + 1][dl];
            o.z = T[hw4 + 2][dl];
            o.w = T[hw4 + 3][dl];
            __builtin_nontemporal_store(o, (vfloat4*)(outb + d * 256 + hw4));
        }
        __syncthreads();
    }
}

// ---------------------------------------------------------------------------
extern "C" void kernel_launch(void* const* d_in, const int* in_sizes, int n_in,
                              void* d_out, int out_size, void* d_ws, size_t ws_size,
                              hipStream_t stream) {
    const int*   seq   = (const int*)d_in[0];    // [256,256] int32
    const int*   seq2  = (const int*)d_in[1];    // [256,256] int32
    const float* alpha = (const float*)d_in[2];  // [1]
    const float* W     = (const float*)d_in[3];  // [1024,256] f32
    float* out = (float*)d_out;                  // [256,256,16,16] f32

    char* ws = (char*)d_ws;
    float* G     = (float*)(ws);                       // 4 MB
    float* norms = (float*)(ws + 4194304);             // 4 KB
    int*   bestV = (int*)(ws + 4194304 + 4096);        // 256 KB

    gram_kernel<<<dim3(16, 16), 256, 0, stream>>>(W, G, norms);
    argmin_bucket_kernel<<<Vn, 256, 0, stream>>>(seq, seq2, alpha, G, norms, bestV);
    write_kernel<<<NT / 32, 256, 0, stream>>>(bestV, W, out);
}

// Round 4
// 123.340 us; speedup vs baseline: 1.2844x; 1.2844x over previous
//
#include <hip/hip_runtime.h>

static constexpr int Vn = 1024;   // codebook size
static constexpr int Dn = 256;    // code dim
static constexpr int NT = 65536;  // B * TOK

typedef float vfloat4 __attribute__((ext_vector_type(4)));  // native vec for stores

// ---------------------------------------------------------------------------
// Kernel 1: G = W * W^T (1024x1024, K=256), fp32. Round-4: 64x32 tiles,
// grid (32,16) = 512 blocks = 2 blocks/CU (round-2 had 1/CU, 1 wave/SIMD --
// all LDS/staging latency and 16 barriers fully exposed). Per thread 2x4
// outputs; per kk: ds_read_b64 (a2, 2-way alias = free) + ds_read_b128
// (b4, 8 addrs x 8-lane bcast, conflict-free) + 8 FMA. Two blocks/CU
// overlap barriers and staging (m114 mechanism).
// EXACTNESS: per output, fmaf chain k=0..255 strictly ascending from 0.0f
// -> bit-identical G/norms to all passing rounds. nt G stores kept.
// ---------------------------------------------------------------------------
__global__ __launch_bounds__(256) void gram_kernel(const float* __restrict__ W,
                                                   float* __restrict__ G,
                                                   float* __restrict__ norms) {
    __shared__ float As[32][68];   // [k-in-chunk][m 0..63], 16B-aligned rows
    __shared__ float Bs[32][36];   // [k-in-chunk][n 0..31], 144B rows (16B-aligned)
    const int tid = threadIdx.x;
    const int tx = tid & 7;        // 0..7  -> 4 consecutive cols
    const int ty = tid >> 3;       // 0..31 -> 2 consecutive rows
    const int bm = blockIdx.y * 64;
    const int bn = blockIdx.x * 32;
    const float4* Wv = (const float4*)W;   // [1024][64] float4

    // staging map: 8 lanes/row (kql), 128 B contiguous global per row/chunk
    const int m0  = tid >> 3;      // 0..31
    const int kql = tid & 7;       // f4 within the 32-k chunk

    float4 pa[2], pb;
#pragma unroll
    for (int s = 0; s < 2; ++s)    // A: 64 rows, 2 per thread
        pa[s] = Wv[(bm + m0 + 32 * s) * 64 + kql];
    pb = Wv[(bn + m0) * 64 + kql]; // B: 32 rows, 1 per thread

    float acc[2][4] = {};
    for (int c = 0; c < 8; ++c) {
        // regs -> LDS, transposed to [k][m]
#pragma unroll
        for (int s = 0; s < 2; ++s) {
            const int m = m0 + 32 * s;
            As[kql * 4 + 0][m] = pa[s].x;
            As[kql * 4 + 1][m] = pa[s].y;
            As[kql * 4 + 2][m] = pa[s].z;
            As[kql * 4 + 3][m] = pa[s].w;
        }
        Bs[kql * 4 + 0][m0] = pb.x;
        Bs[kql * 4 + 1][m0] = pb.y;
        Bs[kql * 4 + 2][m0] = pb.z;
        Bs[kql * 4 + 3][m0] = pb.w;
        __syncthreads();
        if (c < 7) {               // prefetch chunk c+1 under the compute below
            const int kq = (c + 1) * 8 + kql;
#pragma unroll
            for (int s = 0; s < 2; ++s)
                pa[s] = Wv[(bm + m0 + 32 * s) * 64 + kq];
            pb = Wv[(bn + m0) * 64 + kq];
        }
        // inner: b64 + b128 + 8 FMA per kk, register double-buffered frags
        const float* Ab = &As[0][ty * 2];
        const float* Bb = &Bs[0][tx * 4];
        float2 a_c = *(const float2*)Ab;
        float4 b_c = *(const float4*)Bb;
#pragma unroll
        for (int kk = 0; kk < 32; ++kk) {
            const int kn = (kk < 31) ? kk + 1 : kk;       // clamped prefetch
            const float2 a_n = *(const float2*)(Ab + kn * 68);
            const float4 b_n = *(const float4*)(Bb + kn * 36);
            const float a_s[2] = {a_c.x, a_c.y};
            const float b_s[4] = {b_c.x, b_c.y, b_c.z, b_c.w};
#pragma unroll
            for (int u = 0; u < 2; ++u)
#pragma unroll
                for (int w = 0; w < 4; ++w)
                    acc[u][w] = fmaf(a_s[u], b_s[w], acc[u][w]);  // k ascending
            a_c = a_n;
            b_c = b_n;
        }
        __syncthreads();
    }
    // epilogue: nontemporal float4 stores; fused diag -> norms
#pragma unroll
    for (int u = 0; u < 2; ++u) {
        const int row = bm + ty * 2 + u;
        vfloat4 o;
        o.x = acc[u][0]; o.y = acc[u][1]; o.z = acc[u][2]; o.w = acc[u][3];
        __builtin_nontemporal_store(o, (vfloat4*)(G + row * Vn + bn + tx * 4));
        const int cd = row - (bn + tx * 4);
        if (cd >= 0 && cd < 4) norms[row] = acc[u][cd];
    }
}

// ---------------------------------------------------------------------------
// Kernel 2 (FUSED): per-token argmin + direct output write.
// VERBATIM round-2 (bit-exact, passing, ~46 us with write phase hidden by
// cross-block overlap -- do not split). Block = 32 tokens, norms in regs.
// ---------------------------------------------------------------------------
__global__ __launch_bounds__(256) void argmin_write_kernel(const int* __restrict__ seq,
                                                           const int* __restrict__ seq2,
                                                           const float* __restrict__ alpha,
                                                           const float* __restrict__ G,
                                                           const float* __restrict__ norms,
                                                           const float* __restrict__ W,
                                                           float* __restrict__ out) {
    __shared__ float T[32][129];   // [tok][d half], stride 129 -> <=2-way banks
    __shared__ int bestVs[32];
    const int tid = threadIdx.x;
    const int wave = tid >> 6;
    const int lane = tid & 63;
    const int t0 = blockIdx.x * 32;       // first token of block

    float4 nn_r[4];
#pragma unroll
    for (int s = 0; s < 4; ++s) nn_r[s] = ((const float4*)norms)[s * 64 + lane];

    const float a = alpha[0];
    const float c0 = -2.0f * (1.0f - a);
    const float c1 = -2.0f * a;

    // ---- Phase 1: argmin for this wave's 8 tokens --------------------------
    for (int bb = 0; bb < 2; ++bb) {
        const int base_t = t0 + wave * 8 + bb * 4;   // global token of q=0
        const int base_l = wave * 8 + bb * 4;        // block-local
        int iv[4], jv[4];
#pragma unroll
        for (int q = 0; q < 4; ++q) { iv[q] = seq[base_t + q]; jv[q] = seq2[base_t + q]; }
#pragma unroll
        for (int pair = 0; pair < 2; ++pair) {
            const int qa = pair * 2, qb = pair * 2 + 1;
            const float4* GiA = (const float4*)(G + iv[qa] * Vn);
            const float4* GjA = (const float4*)(G + jv[qa] * Vn);
            const float4* GiB = (const float4*)(G + iv[qb] * Vn);
            const float4* GjB = (const float4*)(G + jv[qb] * Vn);
            float4 gia[4], gja[4], gib[4], gjb[4];
#pragma unroll
            for (int s = 0; s < 4; ++s) {
                const int e = s * 64 + lane;
                gia[s] = GiA[e];
                gja[s] = GjA[e];
                gib[s] = GiB[e];
                gjb[s] = GjB[e];
            }
            float bestA = __builtin_inff(), bestB = __builtin_inff();
            int vA = 0, vB = 0;
#pragma unroll
            for (int s = 0; s < 4; ++s) {
                const int e = s * 64 + lane;  // v = 4e..4e+3 ascending per lane
                const float4 nn = nn_r[s];
                const int v = e * 4;
                {
                    const float s0 = fmaf(c1, gja[s].x, fmaf(c0, gia[s].x, nn.x));
                    const float s1 = fmaf(c1, gja[s].y, fmaf(c0, gia[s].y, nn.y));
                    const float s2 = fmaf(c1, gja[s].z, fmaf(c0, gia[s].z, nn.z));
                    const float s3 = fmaf(c1, gja[s].w, fmaf(c0, gia[s].w, nn.w));
                    if (s0 < bestA) { bestA = s0; vA = v; }
                    if (s1 < bestA) { bestA = s1; vA = v + 1; }
                    if (s2 < bestA) { bestA = s2; vA = v + 2; }
                    if (s3 < bestA) { bestA = s3; vA = v + 3; }
                }
                {
                    const float s0 = fmaf(c1, gjb[s].x, fmaf(c0, gib[s].x, nn.x));
                    const float s1 = fmaf(c1, gjb[s].y, fmaf(c0, gib[s].y, nn.y));
                    const float s2 = fmaf(c1, gjb[s].z, fmaf(c0, gib[s].z, nn.z));
                    const float s3 = fmaf(c1, gjb[s].w, fmaf(c0, gib[s].w, nn.w));
                    if (s0 < bestB) { bestB = s0; vB = v; }
                    if (s1 < bestB) { bestB = s1; vB = v + 1; }
                    if (s2 < bestB) { bestB = s2; vB = v + 2; }
                    if (s3 < bestB) { bestB = s3; vB = v + 3; }
                }
            }
#pragma unroll
            for (int off = 32; off >= 1; off >>= 1) {
                const float oa = __shfl_down(bestA, off, 64);
                const int   va = __shfl_down(vA, off, 64);
                if (oa < bestA || (oa == bestA && va < vA)) { bestA = oa; vA = va; }
                const float ob = __shfl_down(bestB, off, 64);
                const int   vb = __shfl_down(vB, off, 64);
                if (ob < bestB || (ob == bestB && vb < vB)) { bestB = ob; vB = vb; }
            }
            if (lane == 0) {
                bestVs[base_l + qa] = vA;
                bestVs[base_l + qb] = vB;
            }
        }
    }
    __syncthreads();

    // ---- Phase 2: two d-halves of 128; T[32][129] --------------------------
    const int b   = t0 >> 8;
    const int hw0 = t0 & 255;
    float* outb = out + b * 65536 + hw0;
    const int tok = tid >> 3;        // 0..31 (gather mapping)
    const int l8  = tid & 7;
    const int hw4  = (tid & 7) * 4;  // 0..28 (write mapping)
    const int drow = tid >> 3;       // 0..31
#pragma unroll
    for (int half = 0; half < 2; ++half) {
        const int v = bestVs[tok];
        const float4* Wr = (const float4*)(W + v * Dn + half * 128);
#pragma unroll
        for (int p = 0; p < 4; ++p) {
            const int d4 = p * 8 + l8;          // local float4 idx, 0..31
            const float4 w4 = Wr[d4];
            T[tok][d4 * 4 + 0] = w4.x;
            T[tok][d4 * 4 + 1] = w4.y;
            T[tok][d4 * 4 + 2] = w4.z;
            T[tok][d4 * 4 + 3] = w4.w;
        }
        __syncthreads();
#pragma unroll
        for (int dp = 0; dp < 128; dp += 32) {
            const int dl = dp + drow;           // local d, 0..127
            const int d = half * 128 + dl;
            vfloat4 o;
            o.x = T[hw4 + 0][dl];
            o.y = T[hw4 + 1][dl];
            o.z = T[hw4 + 2][dl];
            o.w = T[hw4 + 3][dl];
            __builtin_nontemporal_store(o, (vfloat4*)(outb + d * 256 + hw4));
        }
        __syncthreads();
    }
}

// ---------------------------------------------------------------------------
extern "C" void kernel_launch(void* const* d_in, const int* in_sizes, int n_in,
                              void* d_out, int out_size, void* d_ws, size_t ws_size,
                              hipStream_t stream) {
    const int*   seq   = (const int*)d_in[0];    // [256,256] int32
    const int*   seq2  = (const int*)d_in[1];    // [256,256] int32
    const float* alpha = (const float*)d_in[2];  // [1]
    const float* W     = (const float*)d_in[3];  // [1024,256] f32
    float* out = (float*)d_out;                  // [256,256,16,16] f32

    char* ws = (char*)d_ws;
    float* G     = (float*)(ws);             // 4 MB
    float* norms = (float*)(ws + 4194304);   // 4 KB

    gram_kernel<<<dim3(32, 16), 256, 0, stream>>>(W, G, norms);
    argmin_write_kernel<<<NT / 32, 256, 0, stream>>>(seq, seq2, alpha, G, norms, W, out);
}